// Round 1
// baseline (217.144 us; speedup 1.0000x reference)
//
#include <hip/hip_runtime.h>

// FastText negative-sampling loss, MI355X.
// Strategy: 4-lane cluster per row (16 rows/wave, 64 rows/block of 256).
//   - Each lane owns float2 slots {lane4 + 4t : t=0..5} plus slot 24 on lane 0
//     (50 floats = 25 float2; row base is 8B-aligned, so float2 is the widest
//     legal vector load).
//   - Cluster gathers are 32B-consecutive -> ~16 distinct segments per wave
//     load instead of 64 (address-divergence cost /4 vs thread-per-row).
//   - Indices staged coalesced into LDS per block.
//   - Deterministic 2-kernel reduction via d_ws (no atomics, poison-safe).

#define K_POS 6
#define K_NEG 30
#define NGRAMS 12
#define D 50
#define ROWS_PER_BLOCK 64
#define THREADS 256

__device__ __forceinline__ float softplus_f(float x) {
    // stable: max(x,0) + log1p(exp(-|x|))
    return fmaxf(x, 0.f) + log1pf(__expf(-fabsf(x)));
}

// Partial dot of this lane's slice of m against row q (float2-indexed).
__device__ __forceinline__ float dot_slice(const float2* __restrict__ q,
                                           const float2 m[7], int lane4) {
    float p = 0.f;
#pragma unroll
    for (int t = 0; t < 6; ++t) {
        float2 e = q[lane4 + 4 * t];
        p += m[t].x * e.x + m[t].y * e.y;
    }
    if (lane4 == 0) {
        float2 e = q[24];
        p += m[6].x * e.x + m[6].y * e.y;
    }
    return p;
}

extern "C" __global__ void __launch_bounds__(THREADS)
fasttext_main(const int* __restrict__ input_labels,
              const int* __restrict__ pos_labels,
              const int* __restrict__ neg_labels,
              const int* __restrict__ trigram_idx,
              const int* __restrict__ ngram_mask,
              const float* __restrict__ center_W,
              const float* __restrict__ background_W,
              const float* __restrict__ trigram_W,
              float* __restrict__ block_partials)
{
    __shared__ int s_input[ROWS_PER_BLOCK];
    __shared__ int s_tri[ROWS_PER_BLOCK * NGRAMS];
    __shared__ int s_msk[ROWS_PER_BLOCK * NGRAMS];
    __shared__ int s_pos[ROWS_PER_BLOCK * K_POS];
    __shared__ int s_neg[ROWS_PER_BLOCK * K_NEG];

    const int tid = threadIdx.x;
    const int r0 = blockIdx.x * ROWS_PER_BLOCK;

    if (tid < ROWS_PER_BLOCK) s_input[tid] = input_labels[r0 + tid];
#pragma unroll
    for (int i = tid; i < ROWS_PER_BLOCK * NGRAMS; i += THREADS) {
        s_tri[i] = trigram_idx[r0 * NGRAMS + i];
        s_msk[i] = ngram_mask[r0 * NGRAMS + i];
    }
    for (int i = tid; i < ROWS_PER_BLOCK * K_POS; i += THREADS)
        s_pos[i] = pos_labels[r0 * K_POS + i];
#pragma unroll
    for (int i = tid; i < ROWS_PER_BLOCK * K_NEG; i += THREADS)
        s_neg[i] = neg_labels[r0 * K_NEG + i];
    __syncthreads();

    const int cluster = tid >> 2;   // row within block
    const int lane4 = tid & 3;      // dim-slice owner

    // m = center row + masked trigram rows (this lane's slice)
    float2 m[7];
    {
        const float2* q = reinterpret_cast<const float2*>(
            center_W + (size_t)s_input[cluster] * D);
#pragma unroll
        for (int t = 0; t < 6; ++t) m[t] = q[lane4 + 4 * t];
        m[6] = (lane4 == 0) ? q[24] : make_float2(0.f, 0.f);
    }
    for (int n = 0; n < NGRAMS; ++n) {
        if (s_msk[cluster * NGRAMS + n]) {
            const float2* q = reinterpret_cast<const float2*>(
                trigram_W + (size_t)s_tri[cluster * NGRAMS + n] * D);
#pragma unroll
            for (int t = 0; t < 6; ++t) {
                float2 e = q[lane4 + 4 * t];
                m[t].x += e.x; m[t].y += e.y;
            }
            if (lane4 == 0) {
                float2 e = q[24];
                m[6].x += e.x; m[6].y += e.y;
            }
        }
    }

    float acc = 0.f;
    for (int k = 0; k < K_POS; ++k) {
        const float2* q = reinterpret_cast<const float2*>(
            background_W + (size_t)s_pos[cluster * K_POS + k] * D);
        float p = dot_slice(q, m, lane4);
        p += __shfl_xor(p, 1);
        p += __shfl_xor(p, 2);
        if (lane4 == 0) acc += softplus_f(-p);
    }
    for (int k = 0; k < K_NEG; ++k) {
        const float2* q = reinterpret_cast<const float2*>(
            background_W + (size_t)s_neg[cluster * K_NEG + k] * D);
        float p = dot_slice(q, m, lane4);
        p += __shfl_xor(p, 1);
        p += __shfl_xor(p, 2);
        if (lane4 == 0) acc += softplus_f(p);
    }

    // block reduction (lanes with lane4!=0 contribute 0)
#pragma unroll
    for (int off = 1; off < 64; off <<= 1) acc += __shfl_xor(acc, off);
    __shared__ float s_part[THREADS / 64];
    if ((tid & 63) == 0) s_part[tid >> 6] = acc;
    __syncthreads();
    if (tid == 0)
        block_partials[blockIdx.x] = s_part[0] + s_part[1] + s_part[2] + s_part[3];
}

extern "C" __global__ void __launch_bounds__(256)
fasttext_reduce(const float* __restrict__ partials, float* __restrict__ out, int n)
{
    float acc = 0.f;
    for (int i = threadIdx.x; i < n; i += 256) acc += partials[i];
#pragma unroll
    for (int off = 1; off < 64; off <<= 1) acc += __shfl_xor(acc, off);
    __shared__ float s_part[4];
    if ((threadIdx.x & 63) == 0) s_part[threadIdx.x >> 6] = acc;
    __syncthreads();
    if (threadIdx.x == 0) out[0] = s_part[0] + s_part[1] + s_part[2] + s_part[3];
}

extern "C" void kernel_launch(void* const* d_in, const int* in_sizes, int n_in,
                              void* d_out, int out_size, void* d_ws, size_t ws_size,
                              hipStream_t stream) {
    const int*   input_labels = (const int*)  d_in[0];
    const int*   pos_labels   = (const int*)  d_in[1];
    const int*   neg_labels   = (const int*)  d_in[2];
    const int*   trigram_idx  = (const int*)  d_in[3];
    const int*   ngram_mask   = (const int*)  d_in[4];
    const float* center_W     = (const float*)d_in[5];
    const float* background_W = (const float*)d_in[6];
    const float* trigram_W    = (const float*)d_in[7];
    float* out = (float*)d_out;
    float* partials = (float*)d_ws;   // 1024 floats = 4KB scratch

    const int B = in_sizes[0];                      // 65536
    const int nblocks = B / ROWS_PER_BLOCK;         // 1024

    fasttext_main<<<dim3(nblocks), dim3(THREADS), 0, stream>>>(
        input_labels, pos_labels, neg_labels, trigram_idx, ngram_mask,
        center_W, background_W, trigram_W, partials);
    fasttext_reduce<<<dim3(1), dim3(256), 0, stream>>>(partials, out, nblocks);
}